// Round 7
// baseline (3834.218 us; speedup 1.0000x reference)
//
#include <hip/hip_runtime.h>
#include <stdint.h>

#define NB 8
#define NN 8192
#define NP 2048
#define NSAMP 32
#define NC 64

// ---------------------------------------------------------------------------
// prep: weight transposes for coalesced per-k reads in the fused MLP kernel.
// ---------------------------------------------------------------------------
__global__ __launch_bounds__(256) void prep_kernel(
    const float* __restrict__ w1, const float* __restrict__ w2,
    const float* __restrict__ w3, float* __restrict__ w1t,
    float* __restrict__ w2t, float* __restrict__ w3t)
{
    int j = blockIdx.x * 256 + threadIdx.x;
    if (j < 64*67) { int o = j / 67, k = j % 67; w1t[k*64 + o] = w1[j]; }
    int j2 = j - 64*67;
    if (j2 >= 0 && j2 < 64*64) { int o = j2 >> 6, k = j2 & 63; w2t[k*64 + o] = w2[j2]; }
    int j3 = j2 - 64*64;
    if (j3 >= 0 && j3 < 128*64) { int o = j3 >> 6, k = j3 & 63; w3t[k*128 + o] = w3[j3]; }
}

// ---------------------------------------------------------------------------
// FPS, f32, NO FMA CONTRACTION — VERIFIED CORRECT (round 5/6: Output 0 exact).
// d = ((dx*dx + dy*dy) + dz*dz), each op individually rounded; argmax with
// smallest-index tie-break at every level. DO NOT TOUCH.
// ---------------------------------------------------------------------------
__global__ __launch_bounds__(1024) void fps_kernel(
    const float* __restrict__ xyz, int* __restrict__ fps_idx,
    float* __restrict__ out_newxyz)
{
#pragma clang fp contract(off)
    __shared__ float sx[NN], sy[NN], sz[NN];     // 96 KiB
    __shared__ float rv[16];
    __shared__ int   ri[16];
    __shared__ int   sfar;

    const int b = blockIdx.x;
    const int t = threadIdx.x;
    const float* base = xyz + (size_t)b * NN * 3;

    float px[8], py[8], pz[8], dist[8];
    #pragma unroll
    for (int j = 0; j < 8; j++) {
        int p = t + j * 1024;
        float x = base[p*3+0], y = base[p*3+1], z = base[p*3+2];
        sx[p] = x; sy[p] = y; sz[p] = z;
        px[j] = x; py[j] = y; pz[j] = z;
        dist[j] = 1e10f;
    }
    __syncthreads();

    int far = 0;
    for (int k = 0; k < NP; k++) {
        float fx = sx[far], fy = sy[far], fz = sz[far];
        if (t == 0) {
            fps_idx[b*NP + k] = far;
            out_newxyz[((size_t)b*NP + k)*3 + 0] = fx;
            out_newxyz[((size_t)b*NP + k)*3 + 1] = fy;
            out_newxyz[((size_t)b*NP + k)*3 + 2] = fz;
        }
        float best = -1.0f; int bi = 0;
        #pragma unroll
        for (int j = 0; j < 8; j++) {
            float dx = px[j] - fx;
            float dy = py[j] - fy;
            float dz = pz[j] - fz;
            float d = (dx*dx + dy*dy) + dz*dz;   // contract(off): 5 rounded ops
            float nd = fminf(dist[j], d);
            dist[j] = nd;
            if (nd > best) { best = nd; bi = t + j * 1024; }  // strict > keeps lowest idx
        }
        #pragma unroll
        for (int m = 1; m < 64; m <<= 1) {
            float ov = __shfl_xor(best, m);
            int   oi = __shfl_xor(bi, m);
            if (ov > best || (ov == best && oi < bi)) { best = ov; bi = oi; }
        }
        int w = t >> 6;
        if ((t & 63) == 0) { rv[w] = best; ri[w] = bi; }
        __syncthreads();
        if (t < 64) {
            float v  = (t < 16) ? rv[t] : -1.0f;
            int   i2 = (t < 16) ? ri[t] : 0;
            #pragma unroll
            for (int m = 1; m < 16; m <<= 1) {
                float ov = __shfl_xor(v, m);
                int   oi = __shfl_xor(i2, m);
                if (ov > v || (ov == v && oi < i2)) { v = ov; i2 = oi; }
            }
            if (t == 0) sfar = i2;
        }
        __syncthreads();
        far = sfar;
    }
}

// ---------------------------------------------------------------------------
// Fused ball-query + group + 3-layer MLP + max-pool. One wave per query.
// ROUND 7 ball-query d2, mirroring the numpy port's per-ufunc rounding:
//   pp, qq : separate-op sums  rn(rn(x^2+y^2)+z^2)      [np.sum(x**2,-1)]
//   dot    : FMA chain fmaf(qz,pz, fmaf(qy,py, qx*px))  [np.einsum, gcc fp-contract]
//   d2     : rn(rn(qq+pp) - rn(2*dot)); member iff d2 < 0.04f (strict)
// First-32-in-index-order, pad with first hit. MLP in f32 (fmaf).
// ---------------------------------------------------------------------------
__global__ __launch_bounds__(64) void fused_kernel(
    const float* __restrict__ xyz, const float* __restrict__ features,
    const int* __restrict__ fps_idx,
    const float* __restrict__ w1t, const float* __restrict__ b1,
    const float* __restrict__ w2t, const float* __restrict__ b2,
    const float* __restrict__ w3t, const float* __restrict__ b3,
    float* __restrict__ out_feat)
{
#pragma clang fp contract(off)
    constexpr int XP = 36;
    __shared__ __align__(16) float Xs[67 * XP];
    __shared__ __align__(16) float Hs[64 * XP];
    __shared__ int ids[NSAMP];

    const int q = blockIdx.x;           // b*NP + s
    const int b = q >> 11, s = q & (NP - 1);
    const int lane = threadIdx.x;
    const float* base = xyz + (size_t)b * NN * 3;

    // ---- ball query (one wave) ----
    int qi = fps_idx[q];
    float qx = base[qi*3+0], qy = base[qi*3+1], qz = base[qi*3+2];
    float qq = (qx*qx + qy*qy) + qz*qz;              // separate-op (contract off)
    const float RR = 0.04f;                          // f32(0.2*0.2), strict <

    int have = 0, first = 0;
    for (int c = 0; c < NN / 64; c++) {
        int p = c * 64 + lane;
        float px = base[p*3+0], py = base[p*3+1], pz = base[p*3+2];
        float pp  = (px*px + py*py) + pz*pz;         // separate-op
        float dot = fmaf(qz, pz, fmaf(qy, py, qx*px));  // einsum FMA chain
        float d2  = (qq + pp) - 2.0f*dot;            // separate-op
        bool pred = d2 < RR;
        unsigned long long m = __ballot(pred);
        if (have == 0 && m) first = c * 64 + (int)__builtin_ctzll(m);
        if (pred) {
            int rank = have + (int)__popcll(m & ((1ULL << lane) - 1ULL));
            if (rank < NSAMP) ids[rank] = p;
        }
        have += (int)__popcll(m);
        if (have >= NSAMP) break;
    }
    if (lane < NSAMP && lane >= have) ids[lane] = first;
    __syncthreads();

    // ---- build X: rows 0..2 = grouped_xyz - center, rows 3..66 = features ----
    if (lane < NSAMP) {
        int id = ids[lane];
        Xs[0*XP + lane] = base[id*3+0] - qx;
        Xs[1*XP + lane] = base[id*3+1] - qy;
        Xs[2*XP + lane] = base[id*3+2] - qz;
    }
    {
        const float* frow = features + ((size_t)b * NC + lane) * NN;
        #pragma unroll
        for (int n0 = 0; n0 < NSAMP; n0 += 4) {
            float4 v;
            v.x = frow[ids[n0+0]];
            v.y = frow[ids[n0+1]];
            v.z = frow[ids[n0+2]];
            v.w = frow[ids[n0+3]];
            *(float4*)&Xs[(3 + lane) * XP + n0] = v;
        }
    }
    __syncthreads();

    float acc[32];
    // ---- layer 1: 67 -> 64 ----
    {
        float bias = b1[lane];
        #pragma unroll
        for (int n = 0; n < 32; n++) acc[n] = bias;
        for (int k = 0; k < 67; k++) {
            float w = w1t[k*64 + lane];
            const float4* xr = (const float4*)&Xs[k * XP];
            #pragma unroll
            for (int n4 = 0; n4 < 8; n4++) {
                float4 xv = xr[n4];
                acc[n4*4+0] = fmaf(w, xv.x, acc[n4*4+0]);
                acc[n4*4+1] = fmaf(w, xv.y, acc[n4*4+1]);
                acc[n4*4+2] = fmaf(w, xv.z, acc[n4*4+2]);
                acc[n4*4+3] = fmaf(w, xv.w, acc[n4*4+3]);
            }
        }
        #pragma unroll
        for (int n0 = 0; n0 < 32; n0 += 4) {
            float4 v;
            v.x = fmaxf(acc[n0+0], 0.f); v.y = fmaxf(acc[n0+1], 0.f);
            v.z = fmaxf(acc[n0+2], 0.f); v.w = fmaxf(acc[n0+3], 0.f);
            *(float4*)&Hs[lane * XP + n0] = v;
        }
    }
    __syncthreads();
    // ---- layer 2: 64 -> 64 (output into Xs rows 0..63) ----
    {
        float bias = b2[lane];
        #pragma unroll
        for (int n = 0; n < 32; n++) acc[n] = bias;
        for (int k = 0; k < 64; k++) {
            float w = w2t[k*64 + lane];
            const float4* xr = (const float4*)&Hs[k * XP];
            #pragma unroll
            for (int n4 = 0; n4 < 8; n4++) {
                float4 xv = xr[n4];
                acc[n4*4+0] = fmaf(w, xv.x, acc[n4*4+0]);
                acc[n4*4+1] = fmaf(w, xv.y, acc[n4*4+1]);
                acc[n4*4+2] = fmaf(w, xv.z, acc[n4*4+2]);
                acc[n4*4+3] = fmaf(w, xv.w, acc[n4*4+3]);
            }
        }
        __syncthreads();
        #pragma unroll
        for (int n0 = 0; n0 < 32; n0 += 4) {
            float4 v;
            v.x = fmaxf(acc[n0+0], 0.f); v.y = fmaxf(acc[n0+1], 0.f);
            v.z = fmaxf(acc[n0+2], 0.f); v.w = fmaxf(acc[n0+3], 0.f);
            *(float4*)&Xs[lane * XP + n0] = v;
        }
    }
    __syncthreads();
    // ---- layer 3: 64 -> 128 (2 ch/lane) + max-pool + relu ----
    {
        float accA[32], accB[32];
        float ba = b3[lane], bb = b3[lane + 64];
        #pragma unroll
        for (int n = 0; n < 32; n++) { accA[n] = ba; accB[n] = bb; }
        for (int k = 0; k < 64; k++) {
            float wa = w3t[k*128 + lane];
            float wb = w3t[k*128 + lane + 64];
            const float4* xr = (const float4*)&Xs[k * XP];
            #pragma unroll
            for (int n4 = 0; n4 < 8; n4++) {
                float4 xv = xr[n4];
                accA[n4*4+0] = fmaf(wa, xv.x, accA[n4*4+0]);
                accA[n4*4+1] = fmaf(wa, xv.y, accA[n4*4+1]);
                accA[n4*4+2] = fmaf(wa, xv.z, accA[n4*4+2]);
                accA[n4*4+3] = fmaf(wa, xv.w, accA[n4*4+3]);
                accB[n4*4+0] = fmaf(wb, xv.x, accB[n4*4+0]);
                accB[n4*4+1] = fmaf(wb, xv.y, accB[n4*4+1]);
                accB[n4*4+2] = fmaf(wb, xv.z, accB[n4*4+2]);
                accB[n4*4+3] = fmaf(wb, xv.w, accB[n4*4+3]);
            }
        }
        float mA = accA[0], mB = accB[0];
        #pragma unroll
        for (int n = 1; n < 32; n++) { mA = fmaxf(mA, accA[n]); mB = fmaxf(mB, accB[n]); }
        mA = fmaxf(mA, 0.f); mB = fmaxf(mB, 0.f);
        out_feat[((size_t)b*128 + lane)      * NP + s] = mA;
        out_feat[((size_t)b*128 + lane + 64) * NP + s] = mB;
    }
}

// ---------------------------------------------------------------------------
extern "C" void kernel_launch(void* const* d_in, const int* in_sizes, int n_in,
                              void* d_out, int out_size, void* d_ws, size_t ws_size,
                              hipStream_t stream)
{
    const float* xyz      = (const float*)d_in[0];
    const float* features = (const float*)d_in[1];
    const float* w1 = (const float*)d_in[2];
    const float* b1 = (const float*)d_in[3];
    const float* w2 = (const float*)d_in[4];
    const float* b2 = (const float*)d_in[5];
    const float* w3 = (const float*)d_in[6];
    const float* b3 = (const float*)d_in[7];

    float* out        = (float*)d_out;
    float* out_newxyz = out;                  // (8,2048,3) = 49152 floats
    float* out_feat   = out + NB * NP * 3;    // (8,128,2048)

    char* ws = (char*)d_ws;
    int*   fps_idx = (int*)(ws + 0);          // 16384 i32  -> 65536 B
    float* w1t     = (float*)(ws + 65536);    //  4288 f32
    float* w2t     = (float*)(ws + 82688);    //  4096 f32
    float* w3t     = (float*)(ws + 99072);    //  8192 f32

    prep_kernel<<<65, 256, 0, stream>>>(w1, w2, w3, w1t, w2t, w3t);
    fps_kernel<<<NB, 1024, 0, stream>>>(xyz, fps_idx, out_newxyz);
    fused_kernel<<<NB * NP, 64, 0, stream>>>(xyz, features, fps_idx,
                                             w1t, b1, w2t, b2, w3t, b3, out_feat);
}

// Round 8
// 2382.282 us; speedup vs baseline: 1.6095x; 1.6095x over previous
//
#include <hip/hip_runtime.h>
#include <stdint.h>

#define NB 8
#define NN 8192
#define NP 2048
#define NSAMP 32
#define NC 64

// ---------------------------------------------------------------------------
// prep: weight transposes for coalesced per-k reads in the fused MLP kernel.
// ---------------------------------------------------------------------------
__global__ __launch_bounds__(256) void prep_kernel(
    const float* __restrict__ w1, const float* __restrict__ w2,
    const float* __restrict__ w3, float* __restrict__ w1t,
    float* __restrict__ w2t, float* __restrict__ w3t)
{
    int j = blockIdx.x * 256 + threadIdx.x;
    if (j < 64*67) { int o = j / 67, k = j % 67; w1t[k*64 + o] = w1[j]; }
    int j2 = j - 64*67;
    if (j2 >= 0 && j2 < 64*64) { int o = j2 >> 6, k = j2 & 63; w2t[k*64 + o] = w2[j2]; }
    int j3 = j2 - 64*64;
    if (j3 >= 0 && j3 < 128*64) { int o = j3 >> 6, k = j3 & 63; w3t[k*128 + o] = w3[j3]; }
}

// ---------------------------------------------------------------------------
// FPS v2: 256 threads/batch, 32 contiguous points per lane, DPP reductions,
// ONE barrier per iteration (parity double-buffered cross-wave slots).
// Distance math BIT-IDENTICAL to verified round 7: separate-op f32,
// contract(off): d = ((dx*dx + dy*dy) + dz*dz). Argmax = first occurrence:
//   - within lane: ascending j, strict >
//   - across lanes: equality-candidate + int-min DPP reduce (contiguous ranges)
//   - across waves: strict > merge in wave order (contiguous ranges)
// ---------------------------------------------------------------------------
#define DPP_MAXF(m, CTRL) do { \
    int _s = __builtin_amdgcn_update_dpp(__float_as_int(m), __float_as_int(m), \
                                         CTRL, 0xf, 0xf, false); \
    float _f = __int_as_float(_s); \
    m = fmaxf(m, _f); } while (0)

#define DPP_MINI(c, CTRL) do { \
    int _s = __builtin_amdgcn_update_dpp(c, c, CTRL, 0xf, 0xf, false); \
    c = (_s < c) ? _s : c; } while (0)

__global__ __launch_bounds__(256, 1) void fps_kernel(
    const float* __restrict__ xyz, int* __restrict__ fps_idx,
    float* __restrict__ out_newxyz)
{
#pragma clang fp contract(off)
    __shared__ float sxyz[NN * 3];          // raw copy, 96 KiB
    __shared__ float bv[2][4];
    __shared__ int   bix[2][4];

    const int b = blockIdx.x;
    const int t = threadIdx.x;
    const int lane = t & 63;
    const int w = t >> 6;
    const float* base = xyz + (size_t)b * NN * 3;

    // stage full cloud into LDS (coalesced float4)
    for (int i = t; i < NN * 3 / 4; i += 256)
        ((float4*)sxyz)[i] = ((const float4*)base)[i];
    __syncthreads();

    // own points -> registers (contiguous block per lane)
    const int p0 = t * 32;
    float px[32], py[32], pz[32], dist[32];
    #pragma unroll
    for (int j = 0; j < 32; j++) {
        px[j] = sxyz[(p0 + j) * 3 + 0];
        py[j] = sxyz[(p0 + j) * 3 + 1];
        pz[j] = sxyz[(p0 + j) * 3 + 2];
        dist[j] = 1e10f;
    }

    int far = 0;
    for (int k = 0; k < NP; k++) {
        float fx = sxyz[far * 3 + 0];
        float fy = sxyz[far * 3 + 1];
        float fz = sxyz[far * 3 + 2];
        if (t == 0) {
            fps_idx[b * NP + k] = far;
            out_newxyz[((size_t)b * NP + k) * 3 + 0] = fx;
            out_newxyz[((size_t)b * NP + k) * 3 + 1] = fy;
            out_newxyz[((size_t)b * NP + k) * 3 + 2] = fz;
        }

        // 4 independent (best,idx) chains over ascending 8-point sub-ranges
        float bva0 = -1.f, bva1 = -1.f, bva2 = -1.f, bva3 = -1.f;
        int   bja0 = 0,    bja1 = 0,    bja2 = 0,    bja3 = 0;
        #pragma unroll
        for (int j8 = 0; j8 < 8; j8++) {
            {   int j = j8;
                float dx = px[j] - fx, dy = py[j] - fy, dz = pz[j] - fz;
                float d = (dx*dx + dy*dy) + dz*dz;
                float nd = fminf(dist[j], d); dist[j] = nd;
                if (nd > bva0) { bva0 = nd; bja0 = p0 + j; } }
            {   int j = 8 + j8;
                float dx = px[j] - fx, dy = py[j] - fy, dz = pz[j] - fz;
                float d = (dx*dx + dy*dy) + dz*dz;
                float nd = fminf(dist[j], d); dist[j] = nd;
                if (nd > bva1) { bva1 = nd; bja1 = p0 + j; } }
            {   int j = 16 + j8;
                float dx = px[j] - fx, dy = py[j] - fy, dz = pz[j] - fz;
                float d = (dx*dx + dy*dy) + dz*dz;
                float nd = fminf(dist[j], d); dist[j] = nd;
                if (nd > bva2) { bva2 = nd; bja2 = p0 + j; } }
            {   int j = 24 + j8;
                float dx = px[j] - fx, dy = py[j] - fy, dz = pz[j] - fz;
                float d = (dx*dx + dy*dy) + dz*dz;
                float nd = fminf(dist[j], d); dist[j] = nd;
                if (nd > bva3) { bva3 = nd; bja3 = p0 + j; } }
        }
        // merge chains (ranges ascend; strict > keeps earliest on tie)
        float best = bva0; int bj = bja0;
        if (bva1 > best) { best = bva1; bj = bja1; }
        if (bva2 > best) { best = bva2; bj = bja2; }
        if (bva3 > best) { best = bva3; bj = bja3; }

        // wave max via DPP (row_shr 1,2,4,8 then row_bcast 15,31 -> lane 63)
        float m = best;
        DPP_MAXF(m, 0x111); DPP_MAXF(m, 0x112); DPP_MAXF(m, 0x114);
        DPP_MAXF(m, 0x118); DPP_MAXF(m, 0x142); DPP_MAXF(m, 0x143);
        float wm = __int_as_float(__builtin_amdgcn_readlane(__float_as_int(m), 63));

        // first-occurrence index among max-holders: int-min DPP reduce
        int cand = (best == wm) ? bj : 0x7FFFFFFF;
        DPP_MINI(cand, 0x111); DPP_MINI(cand, 0x112); DPP_MINI(cand, 0x114);
        DPP_MINI(cand, 0x118); DPP_MINI(cand, 0x142); DPP_MINI(cand, 0x143);
        int widx = __builtin_amdgcn_readlane(cand, 63);

        if (lane == 0) { bv[k & 1][w] = wm; bix[k & 1][w] = widx; }
        __syncthreads();

        // redundant 4-way merge on every wave (wave ranges ascend; strict >)
        float v0 = bv[k & 1][0], v1 = bv[k & 1][1];
        float v2 = bv[k & 1][2], v3 = bv[k & 1][3];
        int   i0 = bix[k & 1][0], i1 = bix[k & 1][1];
        int   i2 = bix[k & 1][2], i3 = bix[k & 1][3];
        float gv = v0; int gi = i0;
        if (v1 > gv) { gv = v1; gi = i1; }
        if (v2 > gv) { gv = v2; gi = i2; }
        if (v3 > gv) { gv = v3; gi = i3; }
        far = gi;
    }
}

// ---------------------------------------------------------------------------
// Fused ball-query + group + 3-layer MLP + max-pool. One wave per query.
// VERIFIED round 7 (absmax 0.0). d2: pp/qq separate-op, dot FMA chain,
// d2 separate-op, strict < 0.04f. DO NOT TOUCH.
// ---------------------------------------------------------------------------
__global__ __launch_bounds__(64) void fused_kernel(
    const float* __restrict__ xyz, const float* __restrict__ features,
    const int* __restrict__ fps_idx,
    const float* __restrict__ w1t, const float* __restrict__ b1,
    const float* __restrict__ w2t, const float* __restrict__ b2,
    const float* __restrict__ w3t, const float* __restrict__ b3,
    float* __restrict__ out_feat)
{
#pragma clang fp contract(off)
    constexpr int XP = 36;
    __shared__ __align__(16) float Xs[67 * XP];
    __shared__ __align__(16) float Hs[64 * XP];
    __shared__ int ids[NSAMP];

    const int q = blockIdx.x;           // b*NP + s
    const int b = q >> 11, s = q & (NP - 1);
    const int lane = threadIdx.x;
    const float* base = xyz + (size_t)b * NN * 3;

    // ---- ball query (one wave) ----
    int qi = fps_idx[q];
    float qx = base[qi*3+0], qy = base[qi*3+1], qz = base[qi*3+2];
    float qq = (qx*qx + qy*qy) + qz*qz;              // separate-op (contract off)
    const float RR = 0.04f;                          // f32(0.2*0.2), strict <

    int have = 0, first = 0;
    for (int c = 0; c < NN / 64; c++) {
        int p = c * 64 + lane;
        float px = base[p*3+0], py = base[p*3+1], pz = base[p*3+2];
        float pp  = (px*px + py*py) + pz*pz;         // separate-op
        float dot = fmaf(qz, pz, fmaf(qy, py, qx*px));  // einsum FMA chain
        float d2  = (qq + pp) - 2.0f*dot;            // separate-op
        bool pred = d2 < RR;
        unsigned long long m = __ballot(pred);
        if (have == 0 && m) first = c * 64 + (int)__builtin_ctzll(m);
        if (pred) {
            int rank = have + (int)__popcll(m & ((1ULL << lane) - 1ULL));
            if (rank < NSAMP) ids[rank] = p;
        }
        have += (int)__popcll(m);
        if (have >= NSAMP) break;
    }
    if (lane < NSAMP && lane >= have) ids[lane] = first;
    __syncthreads();

    // ---- build X: rows 0..2 = grouped_xyz - center, rows 3..66 = features ----
    if (lane < NSAMP) {
        int id = ids[lane];
        Xs[0*XP + lane] = base[id*3+0] - qx;
        Xs[1*XP + lane] = base[id*3+1] - qy;
        Xs[2*XP + lane] = base[id*3+2] - qz;
    }
    {
        const float* frow = features + ((size_t)b * NC + lane) * NN;
        #pragma unroll
        for (int n0 = 0; n0 < NSAMP; n0 += 4) {
            float4 v;
            v.x = frow[ids[n0+0]];
            v.y = frow[ids[n0+1]];
            v.z = frow[ids[n0+2]];
            v.w = frow[ids[n0+3]];
            *(float4*)&Xs[(3 + lane) * XP + n0] = v;
        }
    }
    __syncthreads();

    float acc[32];
    // ---- layer 1: 67 -> 64 ----
    {
        float bias = b1[lane];
        #pragma unroll
        for (int n = 0; n < 32; n++) acc[n] = bias;
        for (int k = 0; k < 67; k++) {
            float w = w1t[k*64 + lane];
            const float4* xr = (const float4*)&Xs[k * XP];
            #pragma unroll
            for (int n4 = 0; n4 < 8; n4++) {
                float4 xv = xr[n4];
                acc[n4*4+0] = fmaf(w, xv.x, acc[n4*4+0]);
                acc[n4*4+1] = fmaf(w, xv.y, acc[n4*4+1]);
                acc[n4*4+2] = fmaf(w, xv.z, acc[n4*4+2]);
                acc[n4*4+3] = fmaf(w, xv.w, acc[n4*4+3]);
            }
        }
        #pragma unroll
        for (int n0 = 0; n0 < 32; n0 += 4) {
            float4 v;
            v.x = fmaxf(acc[n0+0], 0.f); v.y = fmaxf(acc[n0+1], 0.f);
            v.z = fmaxf(acc[n0+2], 0.f); v.w = fmaxf(acc[n0+3], 0.f);
            *(float4*)&Hs[lane * XP + n0] = v;
        }
    }
    __syncthreads();
    // ---- layer 2: 64 -> 64 (output into Xs rows 0..63) ----
    {
        float bias = b2[lane];
        #pragma unroll
        for (int n = 0; n < 32; n++) acc[n] = bias;
        for (int k = 0; k < 64; k++) {
            float w = w2t[k*64 + lane];
            const float4* xr = (const float4*)&Hs[k * XP];
            #pragma unroll
            for (int n4 = 0; n4 < 8; n4++) {
                float4 xv = xr[n4];
                acc[n4*4+0] = fmaf(w, xv.x, acc[n4*4+0]);
                acc[n4*4+1] = fmaf(w, xv.y, acc[n4*4+1]);
                acc[n4*4+2] = fmaf(w, xv.z, acc[n4*4+2]);
                acc[n4*4+3] = fmaf(w, xv.w, acc[n4*4+3]);
            }
        }
        __syncthreads();
        #pragma unroll
        for (int n0 = 0; n0 < 32; n0 += 4) {
            float4 v;
            v.x = fmaxf(acc[n0+0], 0.f); v.y = fmaxf(acc[n0+1], 0.f);
            v.z = fmaxf(acc[n0+2], 0.f); v.w = fmaxf(acc[n0+3], 0.f);
            *(float4*)&Xs[lane * XP + n0] = v;
        }
    }
    __syncthreads();
    // ---- layer 3: 64 -> 128 (2 ch/lane) + max-pool + relu ----
    {
        float accA[32], accB[32];
        float ba = b3[lane], bb = b3[lane + 64];
        #pragma unroll
        for (int n = 0; n < 32; n++) { accA[n] = ba; accB[n] = bb; }
        for (int k = 0; k < 64; k++) {
            float wa = w3t[k*128 + lane];
            float wb = w3t[k*128 + lane + 64];
            const float4* xr = (const float4*)&Xs[k * XP];
            #pragma unroll
            for (int n4 = 0; n4 < 8; n4++) {
                float4 xv = xr[n4];
                accA[n4*4+0] = fmaf(wa, xv.x, accA[n4*4+0]);
                accA[n4*4+1] = fmaf(wa, xv.y, accA[n4*4+1]);
                accA[n4*4+2] = fmaf(wa, xv.z, accA[n4*4+2]);
                accA[n4*4+3] = fmaf(wa, xv.w, accA[n4*4+3]);
                accB[n4*4+0] = fmaf(wb, xv.x, accB[n4*4+0]);
                accB[n4*4+1] = fmaf(wb, xv.y, accB[n4*4+1]);
                accB[n4*4+2] = fmaf(wb, xv.z, accB[n4*4+2]);
                accB[n4*4+3] = fmaf(wb, xv.w, accB[n4*4+3]);
            }
        }
        float mA = accA[0], mB = accB[0];
        #pragma unroll
        for (int n = 1; n < 32; n++) { mA = fmaxf(mA, accA[n]); mB = fmaxf(mB, accB[n]); }
        mA = fmaxf(mA, 0.f); mB = fmaxf(mB, 0.f);
        out_feat[((size_t)b*128 + lane)      * NP + s] = mA;
        out_feat[((size_t)b*128 + lane + 64) * NP + s] = mB;
    }
}

// ---------------------------------------------------------------------------
extern "C" void kernel_launch(void* const* d_in, const int* in_sizes, int n_in,
                              void* d_out, int out_size, void* d_ws, size_t ws_size,
                              hipStream_t stream)
{
    const float* xyz      = (const float*)d_in[0];
    const float* features = (const float*)d_in[1];
    const float* w1 = (const float*)d_in[2];
    const float* b1 = (const float*)d_in[3];
    const float* w2 = (const float*)d_in[4];
    const float* b2 = (const float*)d_in[5];
    const float* w3 = (const float*)d_in[6];
    const float* b3 = (const float*)d_in[7];

    float* out        = (float*)d_out;
    float* out_newxyz = out;                  // (8,2048,3) = 49152 floats
    float* out_feat   = out + NB * NP * 3;    // (8,128,2048)

    char* ws = (char*)d_ws;
    int*   fps_idx = (int*)(ws + 0);          // 16384 i32  -> 65536 B
    float* w1t     = (float*)(ws + 65536);    //  4288 f32
    float* w2t     = (float*)(ws + 82688);    //  4096 f32
    float* w3t     = (float*)(ws + 99072);    //  8192 f32

    prep_kernel<<<65, 256, 0, stream>>>(w1, w2, w3, w1t, w2t, w3t);
    fps_kernel<<<NB, 256, 0, stream>>>(xyz, fps_idx, out_newxyz);
    fused_kernel<<<NB * NP, 64, 0, stream>>>(xyz, features, fps_idx,
                                             w1t, b1, w2t, b2, w3t, b3, out_feat);
}